// Round 1
// baseline (773.664 us; speedup 1.0000x reference)
//
#include <hip/hip_runtime.h>

// SelfCrossAttn: b=4, c=512, d=h=w=16 -> N=4096, HEADS=4, scale=128^-0.5
// Stage pipeline (all fp32 this round):
//  K1 qkv_gemm : q/k/v[b,o,n] = sum_c W[o,c] x[b,c,n]          (12 GEMMs 512x4096x512)
//  K2 qk_gemm  : S[qq,kk] = scale * sum_e Q[qq,e] K[kk,e]       (16 NT GEMMs 512x512x1024)
//  K3 softmax  : rows of S
//  K4 pv_gemm  : O[qq,e] = sum_kk P[qq,kk] V[kk,e], scattered   (16 NN GEMMs 512x1024x512)
//                store implements swapaxes(2,3).reshape:
//                y[b, h*128+(e>>3), (e&7)*512+qq] = O[qq,e]
//  K5 proj_gemm: out = Wproj @ y + bproj + x                    (4 GEMMs 512x4096x512)
// Per-(b,h) Q/K/V slabs are contiguous 512x1024 row-major views of conv output.

#define TC 512
#define TN 4096
#define NPB (TC*TN)          // 2097152 per-batch elements
#define ATTN_SCALE 0.08838834764831845f   // 128^-0.5

// ---------------- K1: QKV projection (NN GEMM) ----------------
__global__ __launch_bounds__(256)
void qkv_gemm(const float* __restrict__ x,
              const float* __restrict__ Wq,
              const float* __restrict__ Wk,
              const float* __restrict__ Wv,
              float* __restrict__ q, float* __restrict__ k, float* __restrict__ v)
{
    const int z = blockIdx.z;          // p*4 + b
    const int p = z >> 2, b = z & 3;
    const float* W   = (p == 0) ? Wq : (p == 1) ? Wk : Wv;
    float*       out = ((p == 0) ? q : (p == 1) ? k : v) + b * NPB;
    const float* X   = x + b * NPB;

    const int m0 = blockIdx.y * 64;
    const int n0 = blockIdx.x * 64;

    __shared__ float As[16][68];   // [k][m] transposed
    __shared__ float Bs[16][68];   // [k][n]

    const int tid = threadIdx.x;
    const int tx = tid & 15, ty = tid >> 4;

    float acc[4][4] = {};

    for (int k0 = 0; k0 < TC; k0 += 16) {
        {   // A tile: W[m0+r][k0+c4..+3], store transposed
            const int r = tid >> 2, c4 = (tid & 3) << 2;
            const float4 wv = *(const float4*)&W[(m0 + r) * TC + k0 + c4];
            As[c4 + 0][r] = wv.x; As[c4 + 1][r] = wv.y;
            As[c4 + 2][r] = wv.z; As[c4 + 3][r] = wv.w;
        }
        {   // B tile: X[k0+r][n0+c4..+3], natural
            const int r = tid >> 4, c4 = (tid & 15) << 2;
            *(float4*)&Bs[r][c4] = *(const float4*)&X[(k0 + r) * TN + n0 + c4];
        }
        __syncthreads();
        #pragma unroll
        for (int kk = 0; kk < 16; ++kk) {
            const float4 a  = *(const float4*)&As[kk][ty << 2];
            const float4 bv = *(const float4*)&Bs[kk][tx << 2];
            const float av[4] = {a.x, a.y, a.z, a.w};
            const float bw[4] = {bv.x, bv.y, bv.z, bv.w};
            #pragma unroll
            for (int i = 0; i < 4; ++i)
                #pragma unroll
                for (int j = 0; j < 4; ++j)
                    acc[i][j] += av[i] * bw[j];
        }
        __syncthreads();
    }
    #pragma unroll
    for (int i = 0; i < 4; ++i) {
        float4 o4 = make_float4(acc[i][0], acc[i][1], acc[i][2], acc[i][3]);
        *(float4*)&out[(m0 + (ty << 2) + i) * TN + n0 + (tx << 2)] = o4;
    }
}

// ---------------- K2: S = scale * Q K^T (NT GEMM) ----------------
__global__ __launch_bounds__(256)
void qk_gemm(const float* __restrict__ q, const float* __restrict__ k,
             float* __restrict__ P)
{
    const int z = blockIdx.z;                 // b*4 + h
    const float* Q = q + (size_t)z * 524288;  // 512x1024 slab
    const float* K = k + (size_t)z * 524288;
    float*       S = P + (size_t)z * 262144;  // 512x512

    const int m0 = blockIdx.y * 64;
    const int n0 = blockIdx.x * 64;

    __shared__ float As[16][68];
    __shared__ float Bs[16][68];

    const int tid = threadIdx.x;
    const int tx = tid & 15, ty = tid >> 4;

    float acc[4][4] = {};

    for (int k0 = 0; k0 < 1024; k0 += 16) {
        const int r = tid >> 2, c4 = (tid & 3) << 2;
        {
            const float4 qv = *(const float4*)&Q[(m0 + r) * 1024 + k0 + c4];
            As[c4 + 0][r] = qv.x; As[c4 + 1][r] = qv.y;
            As[c4 + 2][r] = qv.z; As[c4 + 3][r] = qv.w;
        }
        {
            const float4 kv = *(const float4*)&K[(n0 + r) * 1024 + k0 + c4];
            Bs[c4 + 0][r] = kv.x; Bs[c4 + 1][r] = kv.y;
            Bs[c4 + 2][r] = kv.z; Bs[c4 + 3][r] = kv.w;
        }
        __syncthreads();
        #pragma unroll
        for (int kk = 0; kk < 16; ++kk) {
            const float4 a  = *(const float4*)&As[kk][ty << 2];
            const float4 bv = *(const float4*)&Bs[kk][tx << 2];
            const float av[4] = {a.x, a.y, a.z, a.w};
            const float bw[4] = {bv.x, bv.y, bv.z, bv.w};
            #pragma unroll
            for (int i = 0; i < 4; ++i)
                #pragma unroll
                for (int j = 0; j < 4; ++j)
                    acc[i][j] += av[i] * bw[j];
        }
        __syncthreads();
    }
    #pragma unroll
    for (int i = 0; i < 4; ++i) {
        float4 o4 = make_float4(acc[i][0] * ATTN_SCALE, acc[i][1] * ATTN_SCALE,
                                acc[i][2] * ATTN_SCALE, acc[i][3] * ATTN_SCALE);
        *(float4*)&S[(m0 + (ty << 2) + i) * 512 + n0 + (tx << 2)] = o4;
    }
}

// ---------------- K3: row softmax, one wave per 512-row ----------------
__global__ __launch_bounds__(256)
void softmax_rows(float* __restrict__ P)
{
    const int wave = threadIdx.x >> 6;
    const int lane = threadIdx.x & 63;
    const int row  = blockIdx.x * 4 + wave;   // 8192 rows
    float* p = P + (size_t)row * 512;

    float vals[8];
    float m = -1e30f;
    #pragma unroll
    for (int t = 0; t < 8; ++t) { vals[t] = p[lane + t * 64]; m = fmaxf(m, vals[t]); }
    #pragma unroll
    for (int s = 32; s > 0; s >>= 1) m = fmaxf(m, __shfl_xor(m, s));
    float sum = 0.f;
    #pragma unroll
    for (int t = 0; t < 8; ++t) { vals[t] = __expf(vals[t] - m); sum += vals[t]; }
    #pragma unroll
    for (int s = 32; s > 0; s >>= 1) sum += __shfl_xor(sum, s);
    const float inv = 1.f / sum;
    #pragma unroll
    for (int t = 0; t < 8; ++t) p[lane + t * 64] = vals[t] * inv;
}

// ---------------- K4: O = P V (NN GEMM) + transpose-scatter store ----------------
__global__ __launch_bounds__(256)
void pv_gemm(const float* __restrict__ P, const float* __restrict__ v,
             float* __restrict__ y)
{
    const int z = blockIdx.z;            // b*4 + h
    const int b = z >> 2, hh = z & 3;
    const float* Pm = P + (size_t)z * 262144;   // 512x512
    const float* V  = v + (size_t)z * 524288;   // 512x1024 slab
    float*       Y  = y + (size_t)b * NPB;

    const int m0 = blockIdx.y * 64;   // qq
    const int n0 = blockIdx.x * 64;   // e (grid.x = 16)

    __shared__ float smem[64 * 68];
    float (*As)[68] = (float (*)[68])smem;             // [16][68]
    float (*Bs)[68] = (float (*)[68])(smem + 16 * 68); // [16][68]

    const int tid = threadIdx.x;
    const int tx = tid & 15, ty = tid >> 4;

    float acc[4][4] = {};

    for (int k0 = 0; k0 < 512; k0 += 16) {
        {   // A tile: P[m0+r][k0+c4], transposed
            const int r = tid >> 2, c4 = (tid & 3) << 2;
            const float4 pv = *(const float4*)&Pm[(m0 + r) * 512 + k0 + c4];
            As[c4 + 0][r] = pv.x; As[c4 + 1][r] = pv.y;
            As[c4 + 2][r] = pv.z; As[c4 + 3][r] = pv.w;
        }
        {   // B tile: V[k0+r][n0+c4], natural
            const int r = tid >> 4, c4 = (tid & 15) << 2;
            *(float4*)&Bs[r][c4] = *(const float4*)&V[(k0 + r) * 1024 + n0 + c4];
        }
        __syncthreads();
        #pragma unroll
        for (int kk = 0; kk < 16; ++kk) {
            const float4 a  = *(const float4*)&As[kk][ty << 2];
            const float4 bv = *(const float4*)&Bs[kk][tx << 2];
            const float av[4] = {a.x, a.y, a.z, a.w};
            const float bw[4] = {bv.x, bv.y, bv.z, bv.w};
            #pragma unroll
            for (int i = 0; i < 4; ++i)
                #pragma unroll
                for (int j = 0; j < 4; ++j)
                    acc[i][j] += av[i] * bw[j];
        }
        __syncthreads();
    }

    // Transpose tile in LDS so global stores are contiguous along m (=qq).
    float* tile = smem;   // 64x68, [n][m]
    #pragma unroll
    for (int i = 0; i < 4; ++i)
        #pragma unroll
        for (int j = 0; j < 4; ++j)
            tile[((tx << 2) + j) * 68 + (ty << 2) + i] = acc[i][j];
    __syncthreads();

    for (int it = tid; it < 4096; it += 256) {
        const int m = it & 63, n = it >> 6;
        const int e = n0 + n, qq = m0 + m;
        // y[b, hh*128 + (e>>3), (e&7)*512 + qq]
        Y[(hh * 128 + (e >> 3)) * TN + ((e & 7) << 9) + qq] = tile[n * 68 + m];
    }
}

// ---------------- K5: out = Wproj @ y + bproj + x (NN GEMM + epilogue) ----------------
__global__ __launch_bounds__(256)
void proj_gemm(const float* __restrict__ y, const float* __restrict__ Wp,
               const float* __restrict__ bias, const float* __restrict__ x,
               float* __restrict__ out)
{
    const int b = blockIdx.z;
    const float* Y = y + (size_t)b * NPB;
    const float* X = x + (size_t)b * NPB;
    float*       O = out + (size_t)b * NPB;

    const int m0 = blockIdx.y * 64;
    const int n0 = blockIdx.x * 64;

    __shared__ float As[16][68];
    __shared__ float Bs[16][68];

    const int tid = threadIdx.x;
    const int tx = tid & 15, ty = tid >> 4;

    float acc[4][4] = {};

    for (int k0 = 0; k0 < TC; k0 += 16) {
        {
            const int r = tid >> 2, c4 = (tid & 3) << 2;
            const float4 wv = *(const float4*)&Wp[(m0 + r) * TC + k0 + c4];
            As[c4 + 0][r] = wv.x; As[c4 + 1][r] = wv.y;
            As[c4 + 2][r] = wv.z; As[c4 + 3][r] = wv.w;
        }
        {
            const int r = tid >> 4, c4 = (tid & 15) << 2;
            *(float4*)&Bs[r][c4] = *(const float4*)&Y[(k0 + r) * TN + n0 + c4];
        }
        __syncthreads();
        #pragma unroll
        for (int kk = 0; kk < 16; ++kk) {
            const float4 a  = *(const float4*)&As[kk][ty << 2];
            const float4 bv = *(const float4*)&Bs[kk][tx << 2];
            const float av[4] = {a.x, a.y, a.z, a.w};
            const float bw[4] = {bv.x, bv.y, bv.z, bv.w};
            #pragma unroll
            for (int i = 0; i < 4; ++i)
                #pragma unroll
                for (int j = 0; j < 4; ++j)
                    acc[i][j] += av[i] * bw[j];
        }
        __syncthreads();
    }
    #pragma unroll
    for (int i = 0; i < 4; ++i) {
        const int row = m0 + (ty << 2) + i;
        const float bi = bias[row];
        const float4 xr = *(const float4*)&X[row * TN + n0 + (tx << 2)];
        float4 o4 = make_float4(acc[i][0] + bi + xr.x, acc[i][1] + bi + xr.y,
                                acc[i][2] + bi + xr.z, acc[i][3] + bi + xr.w);
        *(float4*)&O[row * TN + n0 + (tx << 2)] = o4;
    }
}

extern "C" void kernel_launch(void* const* d_in, const int* in_sizes, int n_in,
                              void* d_out, int out_size, void* d_ws, size_t ws_size,
                              hipStream_t stream) {
    const float* x     = (const float*)d_in[0];
    const float* Wq    = (const float*)d_in[1];
    const float* Wk    = (const float*)d_in[2];
    const float* Wv    = (const float*)d_in[3];
    const float* Wproj = (const float*)d_in[4];
    const float* bproj = (const float*)d_in[5];
    float* out = (float*)d_out;

    // Workspace layout (floats): q | k | v | P ; y aliases q (q dead after K2).
    float* ws = (float*)d_ws;
    float* q = ws;                       // 8388608
    float* k = ws + 8388608;             // 8388608
    float* v = ws + 16777216;            // 8388608
    float* P = ws + 25165824;            // 4194304  (total 117.4 MB)
    float* y = q;

    qkv_gemm   <<<dim3(64, 8, 12), 256, 0, stream>>>(x, Wq, Wk, Wv, q, k, v);
    qk_gemm    <<<dim3(8, 8, 16),  256, 0, stream>>>(q, k, P);
    softmax_rows<<<dim3(2048),     256, 0, stream>>>(P);
    pv_gemm    <<<dim3(16, 8, 16), 256, 0, stream>>>(P, v, y);
    proj_gemm  <<<dim3(64, 8, 4),  256, 0, stream>>>(y, Wproj, bproj, x, out);
}

// Round 2
// 215.378 us; speedup vs baseline: 3.5921x; 3.5921x over previous
//
#include <hip/hip_runtime.h>
#include <stdint.h>

// SelfCrossAttn bf16-MFMA pipeline. b=4, c=512, N=4096, HEADS=4.
// All GEMMs are NT: C[m][n] = sum_k A[m][k] * B[n][k], both operands k-contiguous.
//  prep : Wq/Wk/Wv/Wproj fp32 -> bf16 ; x[b][c][n] -> xT[b][n][c] bf16
//  K1   : q/k/v[b][o][n] = W @ x      : A=Wb[o][c], B=xT[n][c]          -> bf16
//  K2   : S = scale*Q.K^T per slab    : A=Q[qq][e], B=K[kk][e]          -> fp32
//  K3   : row softmax S -> P bf16
//  T1   : v slabs [kk][e] -> vT [e][kk]
//  K4   : O = P.V : A=P[qq][kk], B=vT[e][kk]; epilogue scatters into yT[n][c]
//         (yT[(e&7)*512+qq][h*128+(e>>3)] = O[qq][e], via LDS tile transpose)
//  K5   : out = Wproj @ y + bias + x  : A=Wpb[o][c], B=yT[n][c]         -> fp32

typedef __attribute__((ext_vector_type(8))) short short8;
typedef __attribute__((ext_vector_type(4))) float f32x4;

typedef const __attribute__((address_space(1))) unsigned int* gas_ptr;
typedef __attribute__((address_space(3))) unsigned int* las_ptr;

#define ATTN_SCALE 0.08838834764831845f   // 128^-0.5

__device__ __forceinline__ unsigned short f2bf(float f) {
    union { float f; unsigned int u; } c; c.f = f;
    unsigned int u = c.u;
    u += 0x7fffu + ((u >> 16) & 1u);      // RNE
    return (unsigned short)(u >> 16);
}

__device__ __forceinline__ void gl_lds16(const void* g, void* l) {
    __builtin_amdgcn_global_load_lds((gas_ptr)(uintptr_t)g, (las_ptr)(uintptr_t)l,
                                     16, 0, 0);
}

// ---- shared MFMA core: 128x128 C-tile, 4 waves, BK=32, 16x16x32 bf16 ----
// sA/sB: [128][32] bf16 (8KB each). A rows = C rows (m), B rows = C cols (n).
template<int LDA, int LDB, int KDIM>
__device__ __forceinline__ void mfma_core(
    const unsigned short* __restrict__ A,
    const unsigned short* __restrict__ B,
    int m0, int n0,
    unsigned short* __restrict__ sA, unsigned short* __restrict__ sB,
    f32x4 acc[4][4])
{
    const int tid  = threadIdx.x;
    const int lane = tid & 63, wave = tid >> 6;
    const int lr = lane >> 2, lc = lane & 3;       // staging: 16 rows x 4 chunks
    const int wm = (wave & 1) * 64, wn = (wave >> 1) * 64;
    const int col = lane & 15, quad = lane >> 4;

    const unsigned short* ga = A + (size_t)(m0 + 32 * wave + lr) * LDA + lc * 8;
    const unsigned short* gb = B + (size_t)(n0 + 32 * wave + lr) * LDB + lc * 8;
    unsigned short* la0 = sA + (32 * wave) * 32;
    unsigned short* la1 = sA + (32 * wave + 16) * 32;
    unsigned short* lb0 = sB + (32 * wave) * 32;
    unsigned short* lb1 = sB + (32 * wave + 16) * 32;

    for (int k0 = 0; k0 < KDIM; k0 += 32) {
        gl_lds16(ga + k0,            la0);
        gl_lds16(ga + k0 + 16 * LDA, la1);
        gl_lds16(gb + k0,            lb0);
        gl_lds16(gb + k0 + 16 * LDB, lb1);
        __syncthreads();
        short8 af[4], bf[4];
        #pragma unroll
        for (int i = 0; i < 4; ++i)
            af[i] = *(const short8*)&sA[(wm + i * 16 + col) * 32 + quad * 8];
        #pragma unroll
        for (int j = 0; j < 4; ++j)
            bf[j] = *(const short8*)&sB[(wn + j * 16 + col) * 32 + quad * 8];
        #pragma unroll
        for (int i = 0; i < 4; ++i)
            #pragma unroll
            for (int j = 0; j < 4; ++j)
                acc[i][j] = __builtin_amdgcn_mfma_f32_16x16x32_bf16(
                    af[i], bf[j], acc[i][j], 0, 0, 0);
        __syncthreads();
    }
}

// ---- prep: convert weights to bf16, Wb = [q|k|v|proj] each 512x512 ----
__global__ __launch_bounds__(256)
void convert_w(const float* __restrict__ Wq, const float* __restrict__ Wk,
               const float* __restrict__ Wv, const float* __restrict__ Wp,
               unsigned short* __restrict__ Wb)
{
    const int idx = blockIdx.x * 256 + threadIdx.x;   // 262144 threads
    const int mat = idx >> 16;
    const int off = (idx & 65535) << 2;
    const float* src = (mat == 0 ? Wq : mat == 1 ? Wk : mat == 2 ? Wv : Wp) + off;
    const float4 f = *(const float4*)src;
    uint2 o;
    o.x = f2bf(f.x) | ((unsigned)f2bf(f.y) << 16);
    o.y = f2bf(f.z) | ((unsigned)f2bf(f.w) << 16);
    *(uint2*)&Wb[mat * 262144 + off] = o;
}

// ---- prep: x[b][c][n] fp32 -> xT[b][n][c] bf16 ----
__global__ __launch_bounds__(256)
void transpose_x(const float* __restrict__ x, unsigned short* __restrict__ xT)
{
    const int b = blockIdx.z;
    const int l = threadIdx.x & 63, w = threadIdx.x >> 6;
    const int n  = blockIdx.x * 64 + l;
    const int c0 = blockIdx.y * 32 + w * 8;
    const float* xp = x + (size_t)b * 2097152 + (size_t)c0 * 4096 + n;
    unsigned int p[4];
    #pragma unroll
    for (int j = 0; j < 4; ++j) {
        const unsigned short a  = f2bf(xp[(2 * j)     * 4096]);
        const unsigned short bb = f2bf(xp[(2 * j + 1) * 4096]);
        p[j] = a | ((unsigned)bb << 16);
    }
    uint4 v; v.x = p[0]; v.y = p[1]; v.z = p[2]; v.w = p[3];
    *(uint4*)&xT[(size_t)b * 2097152 + (size_t)n * 512 + c0] = v;
}

// ---- K1: q/k/v = W @ x (NT vs xT), bf16 out natural [o][n] ----
__global__ __launch_bounds__(256)
void gemm_qkv(const unsigned short* __restrict__ Wb,
              const unsigned short* __restrict__ xT,
              unsigned short* __restrict__ qb, unsigned short* __restrict__ kb,
              unsigned short* __restrict__ vb)
{
    __shared__ unsigned short sA[128 * 32], sB[128 * 32];
    const int z = blockIdx.z, wsel = z >> 2, b = z & 3;
    const unsigned short* A = Wb + wsel * 262144;
    const unsigned short* B = xT + (size_t)b * 2097152;
    unsigned short* C = (wsel == 0 ? qb : wsel == 1 ? kb : vb) + (size_t)b * 2097152;
    const int m0 = blockIdx.y * 128, n0 = blockIdx.x * 128;

    f32x4 z4 = {0.f, 0.f, 0.f, 0.f};
    f32x4 acc[4][4];
    #pragma unroll
    for (int i = 0; i < 4; ++i)
        #pragma unroll
        for (int j = 0; j < 4; ++j) acc[i][j] = z4;

    mfma_core<512, 512, 512>(A, B, m0, n0, sA, sB, acc);

    const int lane = threadIdx.x & 63, wave = threadIdx.x >> 6;
    const int wm = (wave & 1) * 64, wn = (wave >> 1) * 64;
    const int col = lane & 15, quad = lane >> 4;
    #pragma unroll
    for (int i = 0; i < 4; ++i)
        #pragma unroll
        for (int r = 0; r < 4; ++r) {
            const int row = m0 + wm + i * 16 + quad * 4 + r;
            #pragma unroll
            for (int j = 0; j < 4; ++j)
                C[(size_t)row * 4096 + n0 + wn + j * 16 + col] = f2bf(acc[i][j][r]);
        }
}

// ---- K2: S = scale * Q K^T per slab, fp32 out ----
__global__ __launch_bounds__(256)
void gemm_qk(const unsigned short* __restrict__ qb,
             const unsigned short* __restrict__ kb,
             float* __restrict__ S)
{
    __shared__ unsigned short sA[128 * 32], sB[128 * 32];
    const int z = blockIdx.z;
    const unsigned short* A = qb + (size_t)z * 524288;   // [512][1024]
    const unsigned short* B = kb + (size_t)z * 524288;
    float* Sp = S + (size_t)z * 262144;
    const int m0 = blockIdx.y * 128, n0 = blockIdx.x * 128;

    f32x4 z4 = {0.f, 0.f, 0.f, 0.f};
    f32x4 acc[4][4];
    #pragma unroll
    for (int i = 0; i < 4; ++i)
        #pragma unroll
        for (int j = 0; j < 4; ++j) acc[i][j] = z4;

    mfma_core<1024, 1024, 1024>(A, B, m0, n0, sA, sB, acc);

    const int lane = threadIdx.x & 63, wave = threadIdx.x >> 6;
    const int wm = (wave & 1) * 64, wn = (wave >> 1) * 64;
    const int col = lane & 15, quad = lane >> 4;
    #pragma unroll
    for (int i = 0; i < 4; ++i)
        #pragma unroll
        for (int r = 0; r < 4; ++r) {
            const int row = m0 + wm + i * 16 + quad * 4 + r;
            #pragma unroll
            for (int j = 0; j < 4; ++j)
                Sp[(size_t)row * 512 + n0 + wn + j * 16 + col] =
                    acc[i][j][r] * ATTN_SCALE;
        }
}

// ---- K3: row softmax S (fp32) -> P (bf16), one wave per 512-row ----
__global__ __launch_bounds__(256)
void softmax_rows(const float* __restrict__ S, unsigned short* __restrict__ P)
{
    const int wave = threadIdx.x >> 6, lane = threadIdx.x & 63;
    const int row  = blockIdx.x * 4 + wave;          // 8192 rows
    const float* p = S + (size_t)row * 512;
    unsigned short* o = P + (size_t)row * 512;

    float vals[8];
    float m = -1e30f;
    #pragma unroll
    for (int t = 0; t < 8; ++t) { vals[t] = p[lane + t * 64]; m = fmaxf(m, vals[t]); }
    #pragma unroll
    for (int s = 32; s > 0; s >>= 1) m = fmaxf(m, __shfl_xor(m, s));
    float sum = 0.f;
    #pragma unroll
    for (int t = 0; t < 8; ++t) { vals[t] = __expf(vals[t] - m); sum += vals[t]; }
    #pragma unroll
    for (int s = 32; s > 0; s >>= 1) sum += __shfl_xor(sum, s);
    const float inv = 1.f / sum;
    #pragma unroll
    for (int t = 0; t < 8; ++t) o[lane + t * 64] = f2bf(vals[t] * inv);
}

// ---- T1: v slab [kk=512][e=1024] -> vT [e=1024][kk=512] (bf16) ----
__global__ __launch_bounds__(256)
void transpose_v(const unsigned short* __restrict__ vb,
                 unsigned short* __restrict__ vT)
{
    const int z = blockIdx.z;
    const unsigned short* src = vb + (size_t)z * 524288;
    unsigned short* dst = vT + (size_t)z * 524288;
    const int l = threadIdx.x & 63, w = threadIdx.x >> 6;
    const int e   = blockIdx.x * 64 + l;
    const int kk0 = blockIdx.y * 32 + w * 8;
    unsigned int p[4];
    #pragma unroll
    for (int j = 0; j < 4; ++j) {
        const unsigned int a  = src[(size_t)(kk0 + 2 * j)     * 1024 + e];
        const unsigned int bb = src[(size_t)(kk0 + 2 * j + 1) * 1024 + e];
        p[j] = a | (bb << 16);
    }
    uint4 v; v.x = p[0]; v.y = p[1]; v.z = p[2]; v.w = p[3];
    *(uint4*)&dst[(size_t)e * 512 + kk0] = v;
}

// ---- K4: O = P V per slab; scatter into yT[n][c] via LDS tile ----
__global__ __launch_bounds__(256)
void gemm_pv(const unsigned short* __restrict__ Pb,
             const unsigned short* __restrict__ vT,
             unsigned short* __restrict__ yT)
{
    __shared__ unsigned short sT[128 * 136];          // 34816 B; aliases staging
    unsigned short* sA = sT;
    unsigned short* sB = sT + 4096;
    const int z = blockIdx.z, b = z >> 2, hh = z & 3;
    const unsigned short* A = Pb + (size_t)z * 262144;   // [512][512]
    const unsigned short* B = vT + (size_t)z * 524288;   // [1024][512]
    unsigned short* yTb = yT + (size_t)b * 2097152;
    const int m0 = blockIdx.y * 128;   // qq
    const int n0 = blockIdx.x * 128;   // e

    f32x4 z4 = {0.f, 0.f, 0.f, 0.f};
    f32x4 acc[4][4];
    #pragma unroll
    for (int i = 0; i < 4; ++i)
        #pragma unroll
        for (int j = 0; j < 4; ++j) acc[i][j] = z4;

    mfma_core<512, 512, 512>(A, B, m0, n0, sA, sB, acc);

    const int tid = threadIdx.x;
    const int lane = tid & 63, wave = tid >> 6;
    const int wm = (wave & 1) * 64, wn = (wave >> 1) * 64;
    const int col = lane & 15, quad = lane >> 4;

    // D tile -> LDS [qq_local][e_local], pad 136
    #pragma unroll
    for (int i = 0; i < 4; ++i)
        #pragma unroll
        for (int r = 0; r < 4; ++r) {
            const int rr = wm + i * 16 + quad * 4 + r;
            #pragma unroll
            for (int j = 0; j < 4; ++j)
                sT[rr * 136 + wn + j * 16 + col] = f2bf(acc[i][j][r]);
        }
    __syncthreads();

    // pack 16-elem c-runs: yT[(s<<9)+qq][hh*128 + (n0>>3) + tt], tt=0..15
    #pragma unroll
    for (int k = 0; k < 4; ++k) {
        const int rid = k * 256 + tid;       // 0..1023
        const int qq_l = rid >> 3, s = rid & 7;
        const unsigned short* Trow = sT + qq_l * 136;
        unsigned int p[8];
        #pragma unroll
        for (int t = 0; t < 8; ++t) {
            const unsigned int a  = Trow[s + 8 * (2 * t)];
            const unsigned int bb = Trow[s + 8 * (2 * t + 1)];
            p[t] = a | (bb << 16);
        }
        const size_t base = (size_t)((s << 9) + m0 + qq_l) * 512 + hh * 128 + (n0 >> 3);
        uint4 lo; lo.x = p[0]; lo.y = p[1]; lo.z = p[2]; lo.w = p[3];
        uint4 hi; hi.x = p[4]; hi.y = p[5]; hi.z = p[6]; hi.w = p[7];
        *(uint4*)&yTb[base]     = lo;
        *(uint4*)&yTb[base + 8] = hi;
    }
}

// ---- K5: out = Wproj @ y + bias + x (NT vs yT), fp32 out ----
__global__ __launch_bounds__(256)
void gemm_proj(const unsigned short* __restrict__ Wpb,
               const unsigned short* __restrict__ yT,
               const float* __restrict__ bias, const float* __restrict__ x,
               float* __restrict__ out)
{
    __shared__ unsigned short sA[128 * 32], sB[128 * 32];
    const int b = blockIdx.z;
    const unsigned short* B = yT + (size_t)b * 2097152;  // [4096][512]
    const int m0 = blockIdx.y * 128, n0 = blockIdx.x * 128;

    f32x4 z4 = {0.f, 0.f, 0.f, 0.f};
    f32x4 acc[4][4];
    #pragma unroll
    for (int i = 0; i < 4; ++i)
        #pragma unroll
        for (int j = 0; j < 4; ++j) acc[i][j] = z4;

    mfma_core<512, 512, 512>(Wpb, B, m0, n0, sA, sB, acc);

    const int lane = threadIdx.x & 63, wave = threadIdx.x >> 6;
    const int wm = (wave & 1) * 64, wn = (wave >> 1) * 64;
    const int col = lane & 15, quad = lane >> 4;
    const size_t boff = (size_t)b * 2097152;
    #pragma unroll
    for (int i = 0; i < 4; ++i)
        #pragma unroll
        for (int r = 0; r < 4; ++r) {
            const int row = m0 + wm + i * 16 + quad * 4 + r;
            const float bi = bias[row];
            #pragma unroll
            for (int j = 0; j < 4; ++j) {
                const size_t idx = boff + (size_t)row * 4096 + n0 + wn + j * 16 + col;
                out[idx] = acc[i][j][r] + bi + x[idx];
            }
        }
}

extern "C" void kernel_launch(void* const* d_in, const int* in_sizes, int n_in,
                              void* d_out, int out_size, void* d_ws, size_t ws_size,
                              hipStream_t stream) {
    const float* x     = (const float*)d_in[0];
    const float* Wq    = (const float*)d_in[1];
    const float* Wk    = (const float*)d_in[2];
    const float* Wv    = (const float*)d_in[3];
    const float* Wproj = (const float*)d_in[4];
    const float* bproj = (const float*)d_in[5];
    float* out = (float*)d_out;

    // workspace (bytes):
    char* w = (char*)d_ws;
    unsigned short* xT = (unsigned short*)(w + 0);          // 16 MB [b][n][c]
    unsigned short* qb = (unsigned short*)(w + 16777216);   // 16 MB [b][o][n]
    unsigned short* kb = (unsigned short*)(w + 33554432);   // 16 MB
    unsigned short* vb = (unsigned short*)(w + 50331648);   // 16 MB
    unsigned short* vT = (unsigned short*)(w + 67108864);   // 16 MB [slab][e][kk]
    float*          S  = (float*)        (w + 83886080);    // 16 MB fp32
    unsigned short* Pb = (unsigned short*)(w + 100663296);  //  8 MB
    unsigned short* Wb = (unsigned short*)(w + 109051904);  //  2 MB
    unsigned short* yT = xT;   // x dead after K1; yT[b][n][c]

    convert_w   <<<dim3(1024),        256, 0, stream>>>(Wq, Wk, Wv, Wproj, Wb);
    transpose_x <<<dim3(64, 16, 4),   256, 0, stream>>>(x, xT);
    gemm_qkv    <<<dim3(32, 4, 12),   256, 0, stream>>>(Wb, xT, qb, kb, vb);
    gemm_qk     <<<dim3(4, 4, 16),    256, 0, stream>>>(qb, kb, S);
    softmax_rows<<<dim3(2048),        256, 0, stream>>>(S, Pb);
    transpose_v <<<dim3(16, 16, 16),  256, 0, stream>>>(vb, vT);
    gemm_pv     <<<dim3(8, 4, 16),    256, 0, stream>>>(Pb, vT, yT);
    gemm_proj   <<<dim3(32, 4, 4),    256, 0, stream>>>(Wb + 3 * 262144, yT, bproj, x, out);
}

// Round 4
// 210.122 us; speedup vs baseline: 3.6820x; 1.0250x over previous
//
#include <hip/hip_runtime.h>
#include <stdint.h>

// SelfCrossAttn bf16-MFMA pipeline v4. b=4, c=512, N=4096, HEADS=4.
// All GEMMs NT: C[m][n] = sum_k A[m][k]*B[n][k], operands k-contiguous.
// Key-index permutation: attention key kk = 4t+s (t=c&127, s=n>>10) is
// re-indexed as kk' = s*128+t uniformly in P and vT' (sum order-agnostic),
// making the fused V-transpose epilogue write contiguous kk'-runs.
//  prep    : W* fp32->bf16 (Wb) ; x[b][c][n] -> xT[b][n][c] bf16
//  gemm_qkv: q/k[b][o][n] bf16 natural; V written as vT'[slab][e][kk']
//  gemm_qk : S[qq][kk'] = scale*Q.K^T, K rows staged via kk'->phys perm
//  softmax : rows of S -> P bf16 (kk' order preserved)
//  gemm_pv : O = P.V' (A=P[qq][kk'], B=vT'[e][kk']); scatters into yT[n][c]
//  gemm_proj: out = Wproj @ y + bias + x (NT vs yT), fp32

typedef __attribute__((ext_vector_type(8))) short short8;
typedef __attribute__((ext_vector_type(4))) float f32x4;

typedef const __attribute__((address_space(1))) unsigned int* gas_ptr;
typedef __attribute__((address_space(3))) unsigned int* las_ptr;

#define ATTN_SCALE 0.08838834764831845f   // 128^-0.5

__device__ __forceinline__ unsigned short f2bf(float f) {
    union { float f; unsigned int u; } c; c.f = f;
    unsigned int u = c.u;
    u += 0x7fffu + ((u >> 16) & 1u);      // RNE
    return (unsigned short)(u >> 16);
}

__device__ __forceinline__ void gl_lds16(const void* g, void* l) {
    __builtin_amdgcn_global_load_lds((gas_ptr)(uintptr_t)g, (las_ptr)(uintptr_t)l,
                                     16, 0, 0);
}

// ---- shared MFMA core: 128x128 C-tile, 4 waves, BK=32, 16x16x32 bf16 ----
// PERMB: B rows are logical kk' -> physical slab row 4*(kk'&127) + (kk'>>7).
template<int LDA, int LDB, int KDIM, bool PERMB = false>
__device__ __forceinline__ void mfma_core(
    const unsigned short* __restrict__ A,
    const unsigned short* __restrict__ B,
    int m0, int n0,
    unsigned short* __restrict__ sA, unsigned short* __restrict__ sB,
    f32x4 acc[4][4])
{
    const int tid  = threadIdx.x;
    const int lane = tid & 63, wave = tid >> 6;
    const int lr = lane >> 2, lc = lane & 3;       // staging: 16 rows x 4 chunks
    const int wm = (wave & 1) * 64, wn = (wave >> 1) * 64;
    const int col = lane & 15, quad = lane >> 4;

    const unsigned short* ga = A + (size_t)(m0 + 32 * wave + lr) * LDA + lc * 8;
    int rb0 = n0 + 32 * wave + lr;
    int rb1 = rb0 + 16;
    if (PERMB) {
        rb0 = 4 * (rb0 & 127) + (rb0 >> 7);
        rb1 = 4 * (rb1 & 127) + (rb1 >> 7);
    }
    const unsigned short* gb0 = B + (size_t)rb0 * LDB + lc * 8;
    const unsigned short* gb1 = B + (size_t)rb1 * LDB + lc * 8;

    unsigned short* la0 = sA + (32 * wave) * 32;
    unsigned short* la1 = sA + (32 * wave + 16) * 32;
    unsigned short* lb0 = sB + (32 * wave) * 32;
    unsigned short* lb1 = sB + (32 * wave + 16) * 32;

    for (int k0 = 0; k0 < KDIM; k0 += 32) {
        gl_lds16(ga + k0,            la0);
        gl_lds16(ga + k0 + 16 * LDA, la1);
        gl_lds16(gb0 + k0,           lb0);
        gl_lds16(gb1 + k0,           lb1);
        __syncthreads();
        short8 af[4], bf[4];
        #pragma unroll
        for (int i = 0; i < 4; ++i)
            af[i] = *(const short8*)&sA[(wm + i * 16 + col) * 32 + quad * 8];
        #pragma unroll
        for (int j = 0; j < 4; ++j)
            bf[j] = *(const short8*)&sB[(wn + j * 16 + col) * 32 + quad * 8];
        #pragma unroll
        for (int i = 0; i < 4; ++i)
            #pragma unroll
            for (int j = 0; j < 4; ++j)
                acc[i][j] = __builtin_amdgcn_mfma_f32_16x16x32_bf16(
                    af[i], bf[j], acc[i][j], 0, 0, 0);
        __syncthreads();
    }
}

// ---- prep: z<4 -> transpose x[b][c][n]->xT[b][n][c] bf16 ; z==4 -> W conv ----
__global__ __launch_bounds__(256)
void prep(const float* __restrict__ x,
          const float* __restrict__ Wq, const float* __restrict__ Wk,
          const float* __restrict__ Wv, const float* __restrict__ Wp,
          unsigned short* __restrict__ xT, unsigned short* __restrict__ Wb)
{
    if (blockIdx.z == 4) {
        const int idx = (blockIdx.y * 64 + blockIdx.x) * 256 + threadIdx.x; // 262144
        const int mat = idx >> 16;
        const int off = (idx & 65535) << 2;
        const float* src = (mat == 0 ? Wq : mat == 1 ? Wk : mat == 2 ? Wv : Wp) + off;
        const float4 f = *(const float4*)src;
        uint2 o;
        o.x = f2bf(f.x) | ((unsigned)f2bf(f.y) << 16);
        o.y = f2bf(f.z) | ((unsigned)f2bf(f.w) << 16);
        *(uint2*)&Wb[mat * 262144 + off] = o;
        return;
    }
    const int b = blockIdx.z;
    const int l = threadIdx.x & 63, w = threadIdx.x >> 6;
    const int n  = blockIdx.x * 64 + l;
    const int c0 = blockIdx.y * 32 + w * 8;
    const float* xp = x + (size_t)b * 2097152 + (size_t)c0 * 4096 + n;
    unsigned int p[4];
    #pragma unroll
    for (int j = 0; j < 4; ++j) {
        const unsigned short a  = f2bf(xp[(2 * j)     * 4096]);
        const unsigned short bb = f2bf(xp[(2 * j + 1) * 4096]);
        p[j] = a | ((unsigned)bb << 16);
    }
    uint4 v; v.x = p[0]; v.y = p[1]; v.z = p[2]; v.w = p[3];
    *(uint4*)&xT[(size_t)b * 2097152 + (size_t)n * 512 + c0] = v;
}

// ---- K1: q/k = W @ x natural [o][n]; V written as vT'[slab][e][kk'] ----
__global__ __launch_bounds__(256)
void gemm_qkv(const unsigned short* __restrict__ Wb,
              const unsigned short* __restrict__ xT,
              unsigned short* __restrict__ qb, unsigned short* __restrict__ kb,
              unsigned short* __restrict__ vT)
{
    __shared__ unsigned short smem[128 * 136];   // 34816 B (sA|sB alias front)
    unsigned short* sA = smem;
    unsigned short* sB = smem + 4096;

    const int z = blockIdx.z, wsel = z >> 2, b = z & 3;
    const unsigned short* A = Wb + wsel * 262144;
    const unsigned short* B = xT + (size_t)b * 2097152;
    const int m0 = blockIdx.y * 128, n0 = blockIdx.x * 128;

    f32x4 z4 = {0.f, 0.f, 0.f, 0.f};
    f32x4 acc[4][4];
    #pragma unroll
    for (int i = 0; i < 4; ++i)
        #pragma unroll
        for (int j = 0; j < 4; ++j) acc[i][j] = z4;

    mfma_core<512, 512, 512>(A, B, m0, n0, sA, sB, acc);

    const int tid = threadIdx.x;
    const int lane = tid & 63, wave = tid >> 6;
    const int wm = (wave & 1) * 64, wn = (wave >> 1) * 64;
    const int col = lane & 15, quad = lane >> 4;

    if (wsel < 2) {
        unsigned short* C = (wsel == 0 ? qb : kb) + (size_t)b * 2097152;
        #pragma unroll
        for (int i = 0; i < 4; ++i)
            #pragma unroll
            for (int r = 0; r < 4; ++r) {
                const int row = m0 + wm + i * 16 + quad * 4 + r;
                #pragma unroll
                for (int j = 0; j < 4; ++j)
                    C[(size_t)row * 4096 + n0 + wn + j * 16 + col] = f2bf(acc[i][j][r]);
            }
    } else {
        // V tile: m = channel c in [m0,m0+128) -> head h = m0>>7, t = ml;
        // n in [n0,n0+128) -> s = n0>>10 (const), e = (n0&1023) + nl.
        // Write vT'[b*4+h][e][kk'= s*128 + t]: per e-row a contiguous 128-run.
        // LDS tile sT[nl][ml], pad 136 (272 B = 17*16, keeps uint4 alignment).
        #pragma unroll
        for (int i = 0; i < 4; ++i)
            #pragma unroll
            for (int r = 0; r < 4; ++r) {
                const int ml = wm + i * 16 + quad * 4 + r;
                #pragma unroll
                for (int j = 0; j < 4; ++j)
                    smem[(wn + j * 16 + col) * 136 + ml] = f2bf(acc[i][j][r]);
            }
        __syncthreads();
        const int h = m0 >> 7, s = n0 >> 10, e0 = n0 & 1023;
        unsigned short* dst = vT + (size_t)(b * 4 + h) * 524288 + s * 128;
        #pragma unroll
        for (int k2 = 0; k2 < 8; ++k2) {
            const int it = k2 * 256 + tid;       // 0..2047
            const int el = it >> 4, ch = it & 15;
            const uint4 val = *(const uint4*)&smem[el * 136 + ch * 8];
            *(uint4*)&dst[(size_t)(e0 + el) * 512 + ch * 8] = val;
        }
    }
}

// ---- K2: S[qq][kk'] = scale * Q K^T, K rows staged via kk' permutation ----
__global__ __launch_bounds__(256)
void gemm_qk(const unsigned short* __restrict__ qb,
             const unsigned short* __restrict__ kb,
             float* __restrict__ S)
{
    __shared__ unsigned short sA[128 * 32], sB[128 * 32];
    const int z = blockIdx.z;
    const unsigned short* A = qb + (size_t)z * 524288;   // [512][1024]
    const unsigned short* B = kb + (size_t)z * 524288;
    float* Sp = S + (size_t)z * 262144;
    const int m0 = blockIdx.y * 128, n0 = blockIdx.x * 128;

    f32x4 z4 = {0.f, 0.f, 0.f, 0.f};
    f32x4 acc[4][4];
    #pragma unroll
    for (int i = 0; i < 4; ++i)
        #pragma unroll
        for (int j = 0; j < 4; ++j) acc[i][j] = z4;

    mfma_core<1024, 1024, 1024, true>(A, B, m0, n0, sA, sB, acc);

    const int lane = threadIdx.x & 63, wave = threadIdx.x >> 6;
    const int wm = (wave & 1) * 64, wn = (wave >> 1) * 64;
    const int col = lane & 15, quad = lane >> 4;
    #pragma unroll
    for (int i = 0; i < 4; ++i)
        #pragma unroll
        for (int r = 0; r < 4; ++r) {
            const int row = m0 + wm + i * 16 + quad * 4 + r;
            #pragma unroll
            for (int j = 0; j < 4; ++j)
                Sp[(size_t)row * 512 + n0 + wn + j * 16 + col] =
                    acc[i][j][r] * ATTN_SCALE;
        }
}

// ---- K3: row softmax S (fp32) -> P (bf16), one wave per 512-row ----
__global__ __launch_bounds__(256)
void softmax_rows(const float* __restrict__ S, unsigned short* __restrict__ P)
{
    const int wave = threadIdx.x >> 6, lane = threadIdx.x & 63;
    const int row  = blockIdx.x * 4 + wave;          // 8192 rows
    const float* p = S + (size_t)row * 512;
    unsigned short* o = P + (size_t)row * 512;

    float vals[8];
    float m = -1e30f;
    #pragma unroll
    for (int t = 0; t < 8; ++t) { vals[t] = p[lane + t * 64]; m = fmaxf(m, vals[t]); }
    #pragma unroll
    for (int s = 32; s > 0; s >>= 1) m = fmaxf(m, __shfl_xor(m, s));
    float sum = 0.f;
    #pragma unroll
    for (int t = 0; t < 8; ++t) { vals[t] = __expf(vals[t] - m); sum += vals[t]; }
    #pragma unroll
    for (int s = 32; s > 0; s >>= 1) sum += __shfl_xor(sum, s);
    const float inv = 1.f / sum;
    #pragma unroll
    for (int t = 0; t < 8; ++t) o[lane + t * 64] = f2bf(vals[t] * inv);
}

// ---- K4: O = P V' per slab; scatter into yT[n][c] via LDS tile ----
__global__ __launch_bounds__(256)
void gemm_pv(const unsigned short* __restrict__ Pb,
             const unsigned short* __restrict__ vT,
             unsigned short* __restrict__ yT)
{
    __shared__ unsigned short sT[128 * 136];          // 34816 B; aliases staging
    unsigned short* sA = sT;
    unsigned short* sB = sT + 4096;
    const int z = blockIdx.z, b = z >> 2, hh = z & 3;
    const unsigned short* A = Pb + (size_t)z * 262144;   // [512][512] kk'-cols
    const unsigned short* B = vT + (size_t)z * 524288;   // [1024][512] kk'-rows
    unsigned short* yTb = yT + (size_t)b * 2097152;
    const int m0 = blockIdx.y * 128;   // qq
    const int n0 = blockIdx.x * 128;   // e

    f32x4 z4 = {0.f, 0.f, 0.f, 0.f};
    f32x4 acc[4][4];
    #pragma unroll
    for (int i = 0; i < 4; ++i)
        #pragma unroll
        for (int j = 0; j < 4; ++j) acc[i][j] = z4;

    mfma_core<512, 512, 512>(A, B, m0, n0, sA, sB, acc);

    const int tid = threadIdx.x;
    const int lane = tid & 63, wave = tid >> 6;
    const int wm = (wave & 1) * 64, wn = (wave >> 1) * 64;
    const int col = lane & 15, quad = lane >> 4;

    // D tile -> LDS [qq_local][e_local], pad 136
    #pragma unroll
    for (int i = 0; i < 4; ++i)
        #pragma unroll
        for (int r = 0; r < 4; ++r) {
            const int rr = wm + i * 16 + quad * 4 + r;
            #pragma unroll
            for (int j = 0; j < 4; ++j)
                sT[rr * 136 + wn + j * 16 + col] = f2bf(acc[i][j][r]);
        }
    __syncthreads();

    // pack 16-elem c-runs: yT[(s<<9)+qq][hh*128 + (n0>>3) + tt], tt=0..15
    #pragma unroll
    for (int k = 0; k < 4; ++k) {
        const int rid = k * 256 + tid;       // 0..1023
        const int qq_l = rid >> 3, s = rid & 7;
        const unsigned short* Trow = sT + qq_l * 136;
        unsigned int p[8];
        #pragma unroll
        for (int t = 0; t < 8; ++t) {
            const unsigned int a  = Trow[s + 8 * (2 * t)];
            const unsigned int bb = Trow[s + 8 * (2 * t + 1)];
            p[t] = a | (bb << 16);
        }
        const size_t base = (size_t)((s << 9) + m0 + qq_l) * 512 + hh * 128 + (n0 >> 3);
        uint4 lo; lo.x = p[0]; lo.y = p[1]; lo.z = p[2]; lo.w = p[3];
        uint4 hi; hi.x = p[4]; hi.y = p[5]; hi.z = p[6]; hi.w = p[7];
        *(uint4*)&yTb[base]     = lo;
        *(uint4*)&yTb[base + 8] = hi;
    }
}

// ---- K5: out = Wproj @ y + bias + x (NT vs yT), fp32 out ----
__global__ __launch_bounds__(256)
void gemm_proj(const unsigned short* __restrict__ Wpb,
               const unsigned short* __restrict__ yT,
               const float* __restrict__ bias, const float* __restrict__ x,
               float* __restrict__ out)
{
    __shared__ unsigned short sA[128 * 32], sB[128 * 32];
    const int b = blockIdx.z;
    const unsigned short* B = yT + (size_t)b * 2097152;  // [4096][512]
    const int m0 = blockIdx.y * 128, n0 = blockIdx.x * 128;

    f32x4 z4 = {0.f, 0.f, 0.f, 0.f};
    f32x4 acc[4][4];
    #pragma unroll
    for (int i = 0; i < 4; ++i)
        #pragma unroll
        for (int j = 0; j < 4; ++j) acc[i][j] = z4;

    mfma_core<512, 512, 512>(Wpb, B, m0, n0, sA, sB, acc);

    const int lane = threadIdx.x & 63, wave = threadIdx.x >> 6;
    const int wm = (wave & 1) * 64, wn = (wave >> 1) * 64;
    const int col = lane & 15, quad = lane >> 4;
    const size_t boff = (size_t)b * 2097152;
    #pragma unroll
    for (int i = 0; i < 4; ++i)
        #pragma unroll
        for (int r = 0; r < 4; ++r) {
            const int row = m0 + wm + i * 16 + quad * 4 + r;
            const float bi = bias[row];
            #pragma unroll
            for (int j = 0; j < 4; ++j) {
                const size_t idx = boff + (size_t)row * 4096 + n0 + wn + j * 16 + col;
                out[idx] = acc[i][j][r] + bi + x[idx];
            }
        }
}

extern "C" void kernel_launch(void* const* d_in, const int* in_sizes, int n_in,
                              void* d_out, int out_size, void* d_ws, size_t ws_size,
                              hipStream_t stream) {
    const float* x     = (const float*)d_in[0];
    const float* Wq    = (const float*)d_in[1];
    const float* Wk    = (const float*)d_in[2];
    const float* Wv    = (const float*)d_in[3];
    const float* Wproj = (const float*)d_in[4];
    const float* bproj = (const float*)d_in[5];
    float* out = (float*)d_out;

    char* w = (char*)d_ws;
    unsigned short* xT = (unsigned short*)(w + 0);          // 16 MB [b][n][c]
    unsigned short* qb = (unsigned short*)(w + 16777216);   // 16 MB [b][o][n]
    unsigned short* kb = (unsigned short*)(w + 33554432);   // 16 MB
    unsigned short* vT = (unsigned short*)(w + 50331648);   // 16 MB [slab][e][kk']
    float*          S  = (float*)        (w + 67108864);    // 16 MB fp32
    unsigned short* Pb = (unsigned short*)(w + 83886080);   //  8 MB
    unsigned short* Wb = (unsigned short*)(w + 92274688);   //  2 MB
    unsigned short* yT = xT;   // xT dead after gemm_qkv

    prep        <<<dim3(64, 16, 5),  256, 0, stream>>>(x, Wq, Wk, Wv, Wproj, xT, Wb);
    gemm_qkv    <<<dim3(32, 4, 12),  256, 0, stream>>>(Wb, xT, qb, kb, vT);
    gemm_qk     <<<dim3(4, 4, 16),   256, 0, stream>>>(qb, kb, S);
    softmax_rows<<<dim3(2048),       256, 0, stream>>>(S, Pb);
    gemm_pv     <<<dim3(8, 4, 16),   256, 0, stream>>>(Pb, vT, yT);
    gemm_proj   <<<dim3(32, 4, 4),   256, 0, stream>>>(Wb + 3 * 262144, yT, bproj, x, out);
}

// Round 5
// 206.101 us; speedup vs baseline: 3.7538x; 1.0195x over previous
//
#include <hip/hip_runtime.h>
#include <stdint.h>

// SelfCrossAttn bf16-MFMA pipeline v5. b=4, c=512, N=4096, HEADS=4.
// All GEMMs NT: C[m][n] = sum_k A[m][k]*B[n][k], operands k-contiguous.
// kk' = s*128+t permutation (s=n>>10, t=c&127) applied uniformly to P cols
// and vT' rows; sum over kk is order-agnostic.
//  prep    : W* fp32->bf16 (Wb) ; x[b][c][n] -> xT[b][n][c] bf16
//  gemm_qkv: q/k[b][o][n] bf16 natural; V direct-stored as vT'[slab][e][kk']
//            (uint2 per acc tile: lane's 4 acc rows are 4 consecutive kk')
//  gemm_qk : split-K x2: S_half[qq][kk'] partials (fp32), K staged via perm
//  softmax : rows of S0+S1 -> P bf16
//  gemm_pv : O = P.V' (A=P[qq][kk'], B=vT'[e][kk']); scatters into yT[n][c]
//  gemm_proj: out = Wproj @ y + bias + x (NT vs yT), fp32

typedef __attribute__((ext_vector_type(8))) short short8;
typedef __attribute__((ext_vector_type(4))) float f32x4;

typedef const __attribute__((address_space(1))) unsigned int* gas_ptr;
typedef __attribute__((address_space(3))) unsigned int* las_ptr;

#define ATTN_SCALE 0.08838834764831845f   // 128^-0.5

__device__ __forceinline__ unsigned short f2bf(float f) {
    union { float f; unsigned int u; } c; c.f = f;
    unsigned int u = c.u;
    u += 0x7fffu + ((u >> 16) & 1u);      // RNE
    return (unsigned short)(u >> 16);
}

__device__ __forceinline__ void gl_lds16(const void* g, void* l) {
    __builtin_amdgcn_global_load_lds((gas_ptr)(uintptr_t)g, (las_ptr)(uintptr_t)l,
                                     16, 0, 0);
}

// ---- shared MFMA core: 128x128 C-tile, 4 waves, BK=32, 16x16x32 bf16 ----
// PERMB: B rows are logical kk' -> physical slab row 4*(kk'&127) + (kk'>>7).
template<int LDA, int LDB, int KDIM, bool PERMB = false>
__device__ __forceinline__ void mfma_core(
    const unsigned short* __restrict__ A,
    const unsigned short* __restrict__ B,
    int m0, int n0,
    unsigned short* __restrict__ sA, unsigned short* __restrict__ sB,
    f32x4 acc[4][4])
{
    const int tid  = threadIdx.x;
    const int lane = tid & 63, wave = tid >> 6;
    const int lr = lane >> 2, lc = lane & 3;       // staging: 16 rows x 4 chunks
    const int wm = (wave & 1) * 64, wn = (wave >> 1) * 64;
    const int col = lane & 15, quad = lane >> 4;

    const unsigned short* ga = A + (size_t)(m0 + 32 * wave + lr) * LDA + lc * 8;
    int rb0 = n0 + 32 * wave + lr;
    int rb1 = rb0 + 16;
    if (PERMB) {
        rb0 = 4 * (rb0 & 127) + (rb0 >> 7);
        rb1 = 4 * (rb1 & 127) + (rb1 >> 7);
    }
    const unsigned short* gb0 = B + (size_t)rb0 * LDB + lc * 8;
    const unsigned short* gb1 = B + (size_t)rb1 * LDB + lc * 8;

    unsigned short* la0 = sA + (32 * wave) * 32;
    unsigned short* la1 = sA + (32 * wave + 16) * 32;
    unsigned short* lb0 = sB + (32 * wave) * 32;
    unsigned short* lb1 = sB + (32 * wave + 16) * 32;

    for (int k0 = 0; k0 < KDIM; k0 += 32) {
        gl_lds16(ga + k0,            la0);
        gl_lds16(ga + k0 + 16 * LDA, la1);
        gl_lds16(gb0 + k0,           lb0);
        gl_lds16(gb1 + k0,           lb1);
        __syncthreads();
        short8 af[4], bf[4];
        #pragma unroll
        for (int i = 0; i < 4; ++i)
            af[i] = *(const short8*)&sA[(wm + i * 16 + col) * 32 + quad * 8];
        #pragma unroll
        for (int j = 0; j < 4; ++j)
            bf[j] = *(const short8*)&sB[(wn + j * 16 + col) * 32 + quad * 8];
        #pragma unroll
        for (int i = 0; i < 4; ++i)
            #pragma unroll
            for (int j = 0; j < 4; ++j)
                acc[i][j] = __builtin_amdgcn_mfma_f32_16x16x32_bf16(
                    af[i], bf[j], acc[i][j], 0, 0, 0);
        __syncthreads();
    }
}

// ---- prep: z<4 -> transpose x[b][c][n]->xT[b][n][c] bf16 ; z==4 -> W conv ----
__global__ __launch_bounds__(256)
void prep(const float* __restrict__ x,
          const float* __restrict__ Wq, const float* __restrict__ Wk,
          const float* __restrict__ Wv, const float* __restrict__ Wp,
          unsigned short* __restrict__ xT, unsigned short* __restrict__ Wb)
{
    if (blockIdx.z == 4) {
        const int idx = (blockIdx.y * 64 + blockIdx.x) * 256 + threadIdx.x; // 262144
        const int mat = idx >> 16;
        const int off = (idx & 65535) << 2;
        const float* src = (mat == 0 ? Wq : mat == 1 ? Wk : mat == 2 ? Wv : Wp) + off;
        const float4 f = *(const float4*)src;
        uint2 o;
        o.x = f2bf(f.x) | ((unsigned)f2bf(f.y) << 16);
        o.y = f2bf(f.z) | ((unsigned)f2bf(f.w) << 16);
        *(uint2*)&Wb[mat * 262144 + off] = o;
        return;
    }
    const int b = blockIdx.z;
    const int l = threadIdx.x & 63, w = threadIdx.x >> 6;
    const int n  = blockIdx.x * 64 + l;
    const int c0 = blockIdx.y * 32 + w * 8;
    const float* xp = x + (size_t)b * 2097152 + (size_t)c0 * 4096 + n;
    unsigned int p[4];
    #pragma unroll
    for (int j = 0; j < 4; ++j) {
        const unsigned short a  = f2bf(xp[(2 * j)     * 4096]);
        const unsigned short bb = f2bf(xp[(2 * j + 1) * 4096]);
        p[j] = a | ((unsigned)bb << 16);
    }
    uint4 v; v.x = p[0]; v.y = p[1]; v.z = p[2]; v.w = p[3];
    *(uint4*)&xT[(size_t)b * 2097152 + (size_t)n * 512 + c0] = v;
}

// ---- K1: q/k = W @ x natural [o][n]; V direct-stored as vT'[slab][e][kk'] ----
__global__ __launch_bounds__(256)
void gemm_qkv(const unsigned short* __restrict__ Wb,
              const unsigned short* __restrict__ xT,
              unsigned short* __restrict__ qb, unsigned short* __restrict__ kb,
              unsigned short* __restrict__ vT)
{
    __shared__ unsigned short sA[128 * 32], sB[128 * 32];

    const int z = blockIdx.z, wsel = z >> 2, b = z & 3;
    const unsigned short* A = Wb + wsel * 262144;
    const unsigned short* B = xT + (size_t)b * 2097152;
    const int m0 = blockIdx.y * 128, n0 = blockIdx.x * 128;

    f32x4 z4 = {0.f, 0.f, 0.f, 0.f};
    f32x4 acc[4][4];
    #pragma unroll
    for (int i = 0; i < 4; ++i)
        #pragma unroll
        for (int j = 0; j < 4; ++j) acc[i][j] = z4;

    mfma_core<512, 512, 512>(A, B, m0, n0, sA, sB, acc);

    const int lane = threadIdx.x & 63, wave = threadIdx.x >> 6;
    const int wm = (wave & 1) * 64, wn = (wave >> 1) * 64;
    const int col = lane & 15, quad = lane >> 4;

    if (wsel < 2) {
        unsigned short* C = (wsel == 0 ? qb : kb) + (size_t)b * 2097152;
        #pragma unroll
        for (int i = 0; i < 4; ++i)
            #pragma unroll
            for (int r = 0; r < 4; ++r) {
                const int row = m0 + wm + i * 16 + quad * 4 + r;
                #pragma unroll
                for (int j = 0; j < 4; ++j)
                    C[(size_t)row * 4096 + n0 + wn + j * 16 + col] = f2bf(acc[i][j][r]);
            }
    } else {
        // V tile: m = channel c -> head h = m0>>7, t = m&127;
        // n -> s = n0>>10 (const per block), e = (n0&1023) + nl.
        // Lane tile (i,j): 4 acc rows = 4 consecutive kk' = wm+i*16+quad*4+r.
        // Direct uint2 store: vT'[b*4+h][e][kk'_base], no LDS round-trip.
        const int h = m0 >> 7, s = n0 >> 10, e0 = n0 & 1023;
        unsigned short* dst = vT + (size_t)(b * 4 + h) * 524288 + s * 128;
        #pragma unroll
        for (int i = 0; i < 4; ++i) {
            const int kb2 = wm + i * 16 + quad * 4;
            #pragma unroll
            for (int j = 0; j < 4; ++j) {
                const int e = e0 + wn + j * 16 + col;
                uint2 o;
                o.x = f2bf(acc[i][j][0]) | ((unsigned)f2bf(acc[i][j][1]) << 16);
                o.y = f2bf(acc[i][j][2]) | ((unsigned)f2bf(acc[i][j][3]) << 16);
                *(uint2*)&dst[(size_t)e * 512 + kb2] = o;
            }
        }
    }
}

// ---- K2: split-K x2: S_half[qq][kk'] = scale * Q K^T partial ----
__global__ __launch_bounds__(256)
void gemm_qk(const unsigned short* __restrict__ qb,
             const unsigned short* __restrict__ kb,
             float* __restrict__ S)
{
    __shared__ unsigned short sA[128 * 32], sB[128 * 32];
    const int z = blockIdx.z;                 // slab*2 + half
    const int slab = z >> 1, half = z & 1;
    const unsigned short* A = qb + (size_t)slab * 524288 + half * 512;
    const unsigned short* B = kb + (size_t)slab * 524288 + half * 512;
    float* Sp = S + (size_t)half * 4194304 + (size_t)slab * 262144;
    const int m0 = blockIdx.y * 128, n0 = blockIdx.x * 128;

    f32x4 z4 = {0.f, 0.f, 0.f, 0.f};
    f32x4 acc[4][4];
    #pragma unroll
    for (int i = 0; i < 4; ++i)
        #pragma unroll
        for (int j = 0; j < 4; ++j) acc[i][j] = z4;

    mfma_core<1024, 1024, 512, true>(A, B, m0, n0, sA, sB, acc);

    const int lane = threadIdx.x & 63, wave = threadIdx.x >> 6;
    const int wm = (wave & 1) * 64, wn = (wave >> 1) * 64;
    const int col = lane & 15, quad = lane >> 4;
    #pragma unroll
    for (int i = 0; i < 4; ++i)
        #pragma unroll
        for (int r = 0; r < 4; ++r) {
            const int row = m0 + wm + i * 16 + quad * 4 + r;
            #pragma unroll
            for (int j = 0; j < 4; ++j)
                Sp[(size_t)row * 512 + n0 + wn + j * 16 + col] =
                    acc[i][j][r] * ATTN_SCALE;
        }
}

// ---- K3: row softmax of (S0+S1) -> P (bf16), one wave per 512-row ----
__global__ __launch_bounds__(256)
void softmax_rows(const float* __restrict__ S, unsigned short* __restrict__ P)
{
    const int wave = threadIdx.x >> 6, lane = threadIdx.x & 63;
    const int row  = blockIdx.x * 4 + wave;          // 8192 rows
    const float* p0 = S + (size_t)row * 512;
    const float* p1 = p0 + 4194304;
    unsigned short* o = P + (size_t)row * 512;

    float vals[8];
    float m = -1e30f;
    #pragma unroll
    for (int t = 0; t < 8; ++t) {
        vals[t] = p0[lane + t * 64] + p1[lane + t * 64];
        m = fmaxf(m, vals[t]);
    }
    #pragma unroll
    for (int s = 32; s > 0; s >>= 1) m = fmaxf(m, __shfl_xor(m, s));
    float sum = 0.f;
    #pragma unroll
    for (int t = 0; t < 8; ++t) { vals[t] = __expf(vals[t] - m); sum += vals[t]; }
    #pragma unroll
    for (int s = 32; s > 0; s >>= 1) sum += __shfl_xor(sum, s);
    const float inv = 1.f / sum;
    #pragma unroll
    for (int t = 0; t < 8; ++t) o[lane + t * 64] = f2bf(vals[t] * inv);
}

// ---- K4: O = P V' per slab; scatter into yT[n][c] via LDS tile ----
__global__ __launch_bounds__(256)
void gemm_pv(const unsigned short* __restrict__ Pb,
             const unsigned short* __restrict__ vT,
             unsigned short* __restrict__ yT)
{
    __shared__ unsigned short sT[128 * 136];          // 34816 B; aliases staging
    unsigned short* sA = sT;
    unsigned short* sB = sT + 4096;
    const int z = blockIdx.z, b = z >> 2, hh = z & 3;
    const unsigned short* A = Pb + (size_t)z * 262144;   // [512][512] kk'-cols
    const unsigned short* B = vT + (size_t)z * 524288;   // [1024][512] kk'-rows
    unsigned short* yTb = yT + (size_t)b * 2097152;
    const int m0 = blockIdx.y * 128;   // qq
    const int n0 = blockIdx.x * 128;   // e

    f32x4 z4 = {0.f, 0.f, 0.f, 0.f};
    f32x4 acc[4][4];
    #pragma unroll
    for (int i = 0; i < 4; ++i)
        #pragma unroll
        for (int j = 0; j < 4; ++j) acc[i][j] = z4;

    mfma_core<512, 512, 512>(A, B, m0, n0, sA, sB, acc);

    const int tid = threadIdx.x;
    const int lane = tid & 63, wave = tid >> 6;
    const int wm = (wave & 1) * 64, wn = (wave >> 1) * 64;
    const int col = lane & 15, quad = lane >> 4;

    // D tile -> LDS [qq_local][e_local], pad 136
    #pragma unroll
    for (int i = 0; i < 4; ++i)
        #pragma unroll
        for (int r = 0; r < 4; ++r) {
            const int rr = wm + i * 16 + quad * 4 + r;
            #pragma unroll
            for (int j = 0; j < 4; ++j)
                sT[rr * 136 + wn + j * 16 + col] = f2bf(acc[i][j][r]);
        }
    __syncthreads();

    // pack 16-elem c-runs: yT[(s<<9)+qq][hh*128 + (n0>>3) + tt], tt=0..15
    #pragma unroll
    for (int k = 0; k < 4; ++k) {
        const int rid = k * 256 + tid;       // 0..1023
        const int qq_l = rid >> 3, s = rid & 7;
        const unsigned short* Trow = sT + qq_l * 136;
        unsigned int p[8];
        #pragma unroll
        for (int t = 0; t < 8; ++t) {
            const unsigned int a  = Trow[s + 8 * (2 * t)];
            const unsigned int bb = Trow[s + 8 * (2 * t + 1)];
            p[t] = a | (bb << 16);
        }
        const size_t base = (size_t)((s << 9) + m0 + qq_l) * 512 + hh * 128 + (n0 >> 3);
        uint4 lo; lo.x = p[0]; lo.y = p[1]; lo.z = p[2]; lo.w = p[3];
        uint4 hi; hi.x = p[4]; hi.y = p[5]; hi.z = p[6]; hi.w = p[7];
        *(uint4*)&yTb[base]     = lo;
        *(uint4*)&yTb[base + 8] = hi;
    }
}

// ---- K5: out = Wproj @ y + bias + x (NT vs yT), fp32 out ----
__global__ __launch_bounds__(256)
void gemm_proj(const unsigned short* __restrict__ Wpb,
               const unsigned short* __restrict__ yT,
               const float* __restrict__ bias, const float* __restrict__ x,
               float* __restrict__ out)
{
    __shared__ unsigned short sA[128 * 32], sB[128 * 32];
    const int b = blockIdx.z;
    const unsigned short* B = yT + (size_t)b * 2097152;  // [4096][512]
    const int m0 = blockIdx.y * 128, n0 = blockIdx.x * 128;

    f32x4 z4 = {0.f, 0.f, 0.f, 0.f};
    f32x4 acc[4][4];
    #pragma unroll
    for (int i = 0; i < 4; ++i)
        #pragma unroll
        for (int j = 0; j < 4; ++j) acc[i][j] = z4;

    mfma_core<512, 512, 512>(Wpb, B, m0, n0, sA, sB, acc);

    const int lane = threadIdx.x & 63, wave = threadIdx.x >> 6;
    const int wm = (wave & 1) * 64, wn = (wave >> 1) * 64;
    const int col = lane & 15, quad = lane >> 4;
    const size_t boff = (size_t)b * 2097152;
    #pragma unroll
    for (int i = 0; i < 4; ++i)
        #pragma unroll
        for (int r = 0; r < 4; ++r) {
            const int row = m0 + wm + i * 16 + quad * 4 + r;
            const float bi = bias[row];
            #pragma unroll
            for (int j = 0; j < 4; ++j) {
                const size_t idx = boff + (size_t)row * 4096 + n0 + wn + j * 16 + col;
                out[idx] = acc[i][j][r] + bi + x[idx];
            }
        }
}

extern "C" void kernel_launch(void* const* d_in, const int* in_sizes, int n_in,
                              void* d_out, int out_size, void* d_ws, size_t ws_size,
                              hipStream_t stream) {
    const float* x     = (const float*)d_in[0];
    const float* Wq    = (const float*)d_in[1];
    const float* Wk    = (const float*)d_in[2];
    const float* Wv    = (const float*)d_in[3];
    const float* Wproj = (const float*)d_in[4];
    const float* bproj = (const float*)d_in[5];
    float* out = (float*)d_out;

    char* w = (char*)d_ws;
    unsigned short* xT = (unsigned short*)(w + 0);          // 16 MB [b][n][c]
    unsigned short* qb = (unsigned short*)(w + 16777216);   // 16 MB [b][o][n]
    unsigned short* kb = (unsigned short*)(w + 33554432);   // 16 MB
    unsigned short* vT = (unsigned short*)(w + 50331648);   // 16 MB [slab][e][kk']
    float*          S  = (float*)        (w + 67108864);    // 32 MB fp32 (2 halves)
    unsigned short* Pb = (unsigned short*)(w + 100663296);  //  8 MB
    unsigned short* Wb = (unsigned short*)(w + 109051904);  //  2 MB
    unsigned short* yT = xT;   // xT dead after gemm_qkv

    prep        <<<dim3(64, 16, 5),  256, 0, stream>>>(x, Wq, Wk, Wv, Wproj, xT, Wb);
    gemm_qkv    <<<dim3(32, 4, 12),  256, 0, stream>>>(Wb, xT, qb, kb, vT);
    gemm_qk     <<<dim3(4, 4, 32),   256, 0, stream>>>(qb, kb, S);
    softmax_rows<<<dim3(2048),       256, 0, stream>>>(S, Pb);
    gemm_pv     <<<dim3(8, 4, 16),   256, 0, stream>>>(Pb, vT, yT);
    gemm_proj   <<<dim3(32, 4, 4),   256, 0, stream>>>(Wb + 3 * 262144, yT, bproj, x, out);
}